// Round 1
// 57.169 us; speedup vs baseline: 1.0043x; 1.0043x over previous
//
#include <hip/hip_runtime.h>

// DigitCaps (collapsed routing):
//   s[o,d] = (1/512) * sum_n sum_k W[n,o,d,k] * x[n,k]
//   v[o,d] = (s^2/(1+s^2)) * s/(sqrt(s^2+1e-7)+1e-7)
//
// float32. x: [512][8], W: [512][10][16][8], out: [10][16].
//
// v2: same layout-aware coalescing (lanes t..t+3 cover one 128B W line),
// but 1024 threads/block instead of 256. Each thread now does 2 n-iters
// (was 8), and the block has 16 waves (4 waves/SIMD) instead of 4
// (1 wave/SIMD). Rationale: with 40 blocks the grid pins exactly 40 CUs;
// at 1 wave/SIMD the ~900-cycle cold-HBM latency was fully exposed.
// 4x TLP hides it; total W traffic unchanged (read exactly once).

#define N_IN  512
#define N_OUT 10
#define D_OUT 16
#define D_IN  8

__global__ __launch_bounds__(1024) void digitcaps_kernel(
    const float* __restrict__ x,   // [512][8]
    const float* __restrict__ W,   // [512][10][16][8]
    float* __restrict__ out)       // [10][16] flat: o*16 + d
{
    const int b  = blockIdx.x;       // 0..39
    const int o  = b >> 2;           // 0..9
    const int dg = b & 3;            // d-group: d = dg*4 + (t&3)
    const int t  = threadIdx.x;      // 0..1023
    const int dl = t & 3;            // d_local
    const int d  = dg * 4 + dl;
    const int nb = t >> 2;           // base n (0..255)

    float acc = 0.0f;

    #pragma unroll
    for (int i = 0; i < 2; ++i) {
        const int n = nb + 256 * i;  // n = 0..511
        // W[n][o][d][0..7]: 8 contiguous floats; lanes t..t+3 cover 128B line
        const float4* wp = reinterpret_cast<const float4*>(
            W + ((size_t)(n * N_OUT + o) * D_OUT + d) * D_IN);
        const float4* xp = reinterpret_cast<const float4*>(x + (size_t)n * D_IN);
        const float4 w0 = wp[0], w1 = wp[1];
        const float4 x0 = xp[0], x1 = xp[1];
        acc += w0.x * x0.x + w0.y * x0.y + w0.z * x0.z + w0.w * x0.w
             + w1.x * x1.x + w1.y * x1.y + w1.z * x1.z + w1.w * x1.w;
    }

    // Butterfly over the 16 lanes sharing d_local within this wave
    // (lanes differing in bits 2..5 have the same t&3).
    #pragma unroll
    for (int m = 4; m <= 32; m <<= 1)
        acc += __shfl_xor(acc, m, 64);

    // Cross-wave (16 waves) reduction: wsum[wave][d_local]
    __shared__ float wsum[16 * 4];
    const int wave = t >> 6;
    const int lane = t & 63;
    if (lane < 4) wsum[wave * 4 + lane] = acc;
    __syncthreads();

    if (t < 4) {
        float s = 0.0f;
        #pragma unroll
        for (int w = 0; w < 16; ++w) s += wsum[w * 4 + t];
        s *= (1.0f / (float)N_IN);
        const float sq   = s * s;
        const float norm = s / (sqrtf(sq + 1e-7f) + 1e-7f);
        out[o * D_OUT + dg * 4 + t] = (sq / (1.0f + sq)) * norm;
    }
}

extern "C" void kernel_launch(void* const* d_in, const int* in_sizes, int n_in,
                              void* d_out, int out_size, void* d_ws, size_t ws_size,
                              hipStream_t stream) {
    const float* x = (const float*)d_in[0];   // 4096 floats
    const float* W = (const float*)d_in[1];   // 655360 floats
    float* out = (float*)d_out;               // 160 floats
    digitcaps_kernel<<<dim3(N_OUT * 4), dim3(1024), 0, stream>>>(x, W, out);
}